// Round 7
// baseline (385.678 us; speedup 1.0000x reference)
//
#include <hip/hip_runtime.h>

#define LEAKY_SLOPE 0.01f
#define NUM_GRAPHS 512
#define POOL_SPAN 8          // graphs per block staged in LDS (overflow -> global)

typedef __attribute__((ext_vector_type(8))) short short8;   // 8 x bf16 (4 VGPRs)
typedef __attribute__((ext_vector_type(4))) float f32x4;    // MFMA C/D

static __device__ __forceinline__ unsigned short f2bf(float f) {
    unsigned u = __float_as_uint(f);
    u += 0x7FFFu + ((u >> 16) & 1u);
    return (unsigned short)(u >> 16);
}
static __device__ __forceinline__ float bf2f(unsigned short h) {
    return __uint_as_float(((unsigned)h) << 16);
}

static __device__ __forceinline__ int wave_incl_scan(int v, int lane) {
#pragma unroll
    for (int off = 1; off < 64; off <<= 1) {
        int t = __shfl_up(v, off, 64);
        if (lane >= off) v += t;
    }
    return v;
}

// ---------------------------------------------------------------------------
// prep1: range-split: per-NODE dst histogram (global atomics on L2-resident
// rowCnt[N]) | x->bf16 convert | W->Bt pack. Replaces bucket-hist + the
// whole LDS radix machinery.
// ---------------------------------------------------------------------------
__global__ __launch_bounds__(256)
void prep1_kernel(const int* __restrict__ dst, int* __restrict__ rowCnt,
                  int E, int histBlocks,
                  const float* __restrict__ x, unsigned short* __restrict__ xB,
                  int xElems, int xBlocks,
                  const float* __restrict__ W1rel, const float* __restrict__ W1root,
                  const float* __restrict__ W2rel, const float* __restrict__ W2root,
                  unsigned short* __restrict__ Bt1, unsigned short* __restrict__ Bt2) {
    const int bid = blockIdx.x;
    if (bid < histBlocks) {
        const int base = bid * 2048;
#pragma unroll
        for (int i = 0; i < 8; ++i) {
            int e = base + i * 256 + threadIdx.x;
            if (e < E) atomicAdd(&rowCnt[dst[e]], 1);
        }
    } else if (bid < histBlocks + xBlocks) {
        int i = (bid - histBlocks) * 256 + threadIdx.x;
        if (i < xElems) {
            float4 f = ((const float4*)x)[i];
            ushort4 o = make_ushort4(f2bf(f.x), f2bf(f.y), f2bf(f.z), f2bf(f.w));
            ((ushort4*)xB)[i] = o;
        }
    } else {
        int b2 = bid - histBlocks - xBlocks;            // 0..7
        for (int idx = b2 * 2048 + threadIdx.x; idx < (b2 + 1) * 2048; idx += 256) {
            int which = idx >> 13;
            int j = idx & 8191;
            int n = j >> 7, k = j & 127;
            const float* Wr = which ? W2rel : W1rel;
            const float* Wo = which ? W2root : W1root;
            float v = (k < 64) ? Wr[k * 64 + n] : Wo[(k - 64) * 64 + n];
            (which ? Bt2 : Bt1)[j] = f2bf(v);
        }
    }
}

// ---------------------------------------------------------------------------
// scan1: per-block (512-wide) exclusive scan of rowCnt -> rowStart (local),
// block totals -> blockSum.
// ---------------------------------------------------------------------------
__global__ __launch_bounds__(512)
void scan1_kernel(const int* __restrict__ rowCnt, int* __restrict__ rowStart,
                  int* __restrict__ blockSum, int N) {
    __shared__ int ws[8];
    const int b = blockIdx.x, t = threadIdx.x, lane = t & 63, wid = t >> 6;
    const int i = b * 512 + t;
    int v = (i < N) ? rowCnt[i] : 0;
    int s = wave_incl_scan(v, lane);
    if (lane == 63) ws[wid] = s;
    __syncthreads();
    int add = 0;
    for (int k = 0; k < wid; ++k) add += ws[k];
    int incl = s + add;
    if (i < N) rowStart[i] = incl - v;          // local exclusive
    if (t == 511) blockSum[b] = incl;           // block total
}

// ---------------------------------------------------------------------------
// scan2: one block scans blockSum (<=256 entries) in place -> exclusive
// offsets; sets rowStart[N]=E.
// ---------------------------------------------------------------------------
__global__ __launch_bounds__(256)
void scan2_kernel(int* __restrict__ blockSum, int nBlocks,
                  int* __restrict__ rowStart, int N, int E) {
    __shared__ int ws[4];
    const int t = threadIdx.x, lane = t & 63, wid = t >> 6;
    int v = (t < nBlocks) ? blockSum[t] : 0;
    int s = wave_incl_scan(v, lane);
    if (lane == 63) ws[wid] = s;
    __syncthreads();
    int add = 0;
    for (int k = 0; k < wid; ++k) add += ws[k];
    if (t < nBlocks) blockSum[t] = s + add - v; // exclusive offset
    if (t == 0) rowStart[N] = E;
}

// ---------------------------------------------------------------------------
// scan3: add block offsets -> final rowStart; init cursor; zero pooled.
// ---------------------------------------------------------------------------
__global__ __launch_bounds__(512)
void scan3_kernel(int* __restrict__ rowStart, const int* __restrict__ blockSum,
                  int* __restrict__ cursor, float* __restrict__ pooled, int N) {
    const int b = blockIdx.x;
    const int i = b * 512 + threadIdx.x;
    if (i < N) {
        int v = rowStart[i] + blockSum[b];
        rowStart[i] = v;
        cursor[i] = v;
    }
    const int tot = gridDim.x * 512;
    for (int j = b * 512 + threadIdx.x; j < NUM_GRAPHS * 64; j += tot)
        pooled[j] = 0.f;
}

// ---------------------------------------------------------------------------
// scatter: single streaming pass; each edge lands directly in its final
// dst-sorted slot via per-node atomic cursor. Run-contiguous positions give
// the scattered 8B writes natural 64B-line locality (~8 entries/line).
// ---------------------------------------------------------------------------
__global__ __launch_bounds__(256)
void scatter_kernel(const int* __restrict__ src, const int* __restrict__ dst,
                    const float* __restrict__ w, int* __restrict__ cursor,
                    int2* __restrict__ edata, int E) {
    const int base = blockIdx.x * 2048;
#pragma unroll
    for (int i = 0; i < 8; ++i) {
        int e = base + i * 256 + threadIdx.x;
        if (e < E) {
            int d = dst[e];
            int p = atomicAdd(&cursor[d], 1);
            edata[p] = make_int2(src[e], __float_as_int(w[e]));
        }
    }
}

// ---------------------------------------------------------------------------
// fused_layer<POOL>: gather + transform (R5 shape, unchanged; edata.x is now
// the plain src id). Block = 32 nodes, 512 threads = 8 waves; wave w gathers
// nodes 4w..4w+3 as 2 pairs with both nodes' loads in flight; transform is
// the 8-way (s,t) tile split.
// ---------------------------------------------------------------------------
template <int POOL>
__global__ __launch_bounds__(512)
void fused_layer(const unsigned short* __restrict__ xin,
                 const int* __restrict__ rowStart,
                 const int2* __restrict__ edata,
                 const unsigned short* __restrict__ Bt,
                 const float* __restrict__ bias,
                 unsigned short* __restrict__ xoutB,
                 const int* __restrict__ batch,
                 float* __restrict__ pooled, int N) {
    const int lane = threadIdx.x & 63;
    const int wave = threadIdx.x >> 6;          // 0..7
    const int grp  = lane >> 4;                 // edge slot in gather / quad in MFMA
    const int l16  = lane & 15;                 // feature-chunk lane / row lane
    const int f4   = l16 * 4;
    const int m0   = (int)blockIdx.x * 32;      // block's node base

    __shared__ __align__(16) unsigned short aggL[32][72];
    __shared__ float lpool[POOL_SPAN * 64];

    int gmin = 0;
    if (POOL) {
        gmin = batch[m0 < N ? m0 : N - 1];
        for (int i = threadIdx.x; i < POOL_SPAN * 64; i += 512) lpool[i] = 0.f;
    }

    // ---- gather phase: wave w owns local nodes 4w .. 4w+3, as 2 pairs ----
    int rsv = 0;
    if (lane <= 32) {
        int rn = m0 + lane;
        rsv = rowStart[rn < N ? rn : N];
    }
#pragma unroll
    for (int p = 0; p < 2; ++p) {
        const int ia = (wave << 2) + (p << 1);     // local node a; b = ia+1
        const int sa = __shfl(rsv, ia, 64);
        const int ea = __shfl(rsv, ia + 1, 64);
        const int sb = ea;
        const int eb = __shfl(rsv, ia + 2, 64);

        float aA0 = 0.f, aA1 = 0.f, aA2 = 0.f, aA3 = 0.f;
        float aB0 = 0.f, aB1 = 0.f, aB2 = 0.f, aB3 = 0.f;
        int ja = sa, jb = sb;
        while (ja < ea || jb < eb) {
            const bool da = ja < ea;
            const bool db = jb < eb;
            int2 edA[4], edB[4];
            if (da) {
#pragma unroll
                for (int u = 0; u < 4; ++u) {
                    int ii = ja + u * 4 + grp;
                    edA[u] = edata[ii < ea ? ii : sa];
                }
            }
            if (db) {
#pragma unroll
                for (int u = 0; u < 4; ++u) {
                    int ii = jb + u * 4 + grp;
                    edB[u] = edata[ii < eb ? ii : sb];
                }
            }
            ushort4 rA[4], rB[4];
            if (da) {
#pragma unroll
                for (int u = 0; u < 4; ++u)
                    rA[u] = *(const ushort4*)(xin + (size_t)edA[u].x * 64 + f4);
            }
            if (db) {
#pragma unroll
                for (int u = 0; u < 4; ++u)
                    rB[u] = *(const ushort4*)(xin + (size_t)edB[u].x * 64 + f4);
            }
            if (da) {
#pragma unroll
                for (int u = 0; u < 4; ++u) {
                    float wv = (ja + u * 4 + grp < ea) ? __int_as_float(edA[u].y) : 0.0f;
                    aA0 += bf2f(rA[u].x) * wv;  aA1 += bf2f(rA[u].y) * wv;
                    aA2 += bf2f(rA[u].z) * wv;  aA3 += bf2f(rA[u].w) * wv;
                }
                ja += 16;
            }
            if (db) {
#pragma unroll
                for (int u = 0; u < 4; ++u) {
                    float wv = (jb + u * 4 + grp < eb) ? __int_as_float(edB[u].y) : 0.0f;
                    aB0 += bf2f(rB[u].x) * wv;  aB1 += bf2f(rB[u].y) * wv;
                    aB2 += bf2f(rB[u].z) * wv;  aB3 += bf2f(rB[u].w) * wv;
                }
                jb += 16;
            }
        }
        aA0 += __shfl_xor(aA0, 16, 64);  aA1 += __shfl_xor(aA1, 16, 64);
        aA2 += __shfl_xor(aA2, 16, 64);  aA3 += __shfl_xor(aA3, 16, 64);
        aA0 += __shfl_xor(aA0, 32, 64);  aA1 += __shfl_xor(aA1, 32, 64);
        aA2 += __shfl_xor(aA2, 32, 64);  aA3 += __shfl_xor(aA3, 32, 64);
        aB0 += __shfl_xor(aB0, 16, 64);  aB1 += __shfl_xor(aB1, 16, 64);
        aB2 += __shfl_xor(aB2, 16, 64);  aB3 += __shfl_xor(aB3, 16, 64);
        aB0 += __shfl_xor(aB0, 32, 64);  aB1 += __shfl_xor(aB1, 32, 64);
        aB2 += __shfl_xor(aB2, 32, 64);  aB3 += __shfl_xor(aB3, 32, 64);
        if (grp == 0) {
            *(ushort4*)(&aggL[ia][f4]) =
                make_ushort4(f2bf(aA0), f2bf(aA1), f2bf(aA2), f2bf(aA3));
            *(ushort4*)(&aggL[ia + 1][f4]) =
                make_ushort4(f2bf(aB0), f2bf(aB1), f2bf(aB2), f2bf(aB3));
        }
    }

    __syncthreads();   // aggL complete (and lpool zero-init for POOL)

    // ---- transform phase: wave w -> tile (s = w>>2 row half, t = w&3) ----
    {
        const int s = wave >> 2;
        const int t = wave & 3;
        short8 bf[4];
#pragma unroll
        for (int k = 0; k < 4; ++k)
            bf[k] = *(const short8*)(Bt + (t * 16 + l16) * 128 + k * 32 + grp * 8);

        f32x4 acc = (f32x4){0.f, 0.f, 0.f, 0.f};
        int row = m0 + s * 16 + l16;
        int rowc = row < N ? row : N - 1;
        const unsigned short* xrow = xin + (size_t)rowc * 64;
        short8 af[4];
        af[0] = *(const short8*)(&aggL[s * 16 + l16][grp * 8]);
        af[1] = *(const short8*)(&aggL[s * 16 + l16][32 + grp * 8]);
        af[2] = *(const short8*)(xrow + grp * 8);
        af[3] = *(const short8*)(xrow + 32 + grp * 8);
#pragma unroll
        for (int k = 0; k < 4; ++k) {
            if (POOL == 0)
                acc = __builtin_amdgcn_mfma_f32_16x16x32_bf16(bf[k], af[k], acc, 0, 0, 0);
            else
                acc = __builtin_amdgcn_mfma_f32_16x16x32_bf16(af[k], bf[k], acc, 0, 0, 0);
        }

        if (POOL == 0) {
            const int node = m0 + s * 16 + l16;
            if (node < N) {
                const float4 bb = *(const float4*)(bias + t * 16 + grp * 4);
                float v0 = acc[0] + bb.x;
                float v1 = acc[1] + bb.y;
                float v2 = acc[2] + bb.z;
                float v3 = acc[3] + bb.w;
                v0 = (v0 > 0.f) ? v0 : LEAKY_SLOPE * v0;
                v1 = (v1 > 0.f) ? v1 : LEAKY_SLOPE * v1;
                v2 = (v2 > 0.f) ? v2 : LEAKY_SLOPE * v2;
                v3 = (v3 > 0.f) ? v3 : LEAKY_SLOPE * v3;
                ushort4 o = make_ushort4(f2bf(v0), f2bf(v1), f2bf(v2), f2bf(v3));
                *(ushort4*)(xoutB + (size_t)node * 64 + t * 16 + grp * 4) = o;
            }
        } else {
            const int col = t * 16 + l16;
            const float b = bias[col];
            const int rowbase = m0 + s * 16 + grp * 4;
            float v[4]; int g[4]; int nv = 0;
#pragma unroll
            for (int r = 0; r < 4; ++r) {
                int row2 = rowbase + r;
                if (row2 < N) {
                    float a = acc[r] + b;
                    a = (a > 0.0f) ? a : LEAKY_SLOPE * a;
                    v[nv] = a;
                    g[nv] = batch[row2];
                    ++nv;
                }
            }
            if (nv == 4 && g[0] == g[3]) {
                int gl = g[0] - gmin;
                float sum = v[0] + v[1] + v[2] + v[3];
                if (gl < POOL_SPAN) atomicAdd(&lpool[gl * 64 + col], sum);
                else                atomicAdd(&pooled[g[0] * 64 + col], sum);
            } else {
                for (int r = 0; r < nv; ++r) {
                    int gl = g[r] - gmin;
                    if (gl < POOL_SPAN) atomicAdd(&lpool[gl * 64 + col], v[r]);
                    else                atomicAdd(&pooled[g[r] * 64 + col], v[r]);
                }
            }
        }
    }

    if (POOL) {
        __syncthreads();
        for (int i = threadIdx.x; i < POOL_SPAN * 64; i += 512) {
            float vv = lpool[i];
            if (vv != 0.0f)
                atomicAdd(&pooled[(gmin + (i >> 6)) * 64 + (i & 63)], vv);
        }
    }
}

// ---------------------------------------------------------------------------
// Final: cnt via binary search on sorted batch; tiny GEMM epilogue.
// ---------------------------------------------------------------------------
__global__ __launch_bounds__(64)
void final_kernel(const float* __restrict__ pooled, const int* __restrict__ batch,
                  int N, const float* __restrict__ Wl, const float* __restrict__ bl,
                  float* __restrict__ out) {
    const int g = blockIdx.x;
    const int j = threadIdx.x;
    __shared__ float sp[64];
    __shared__ int scnt;
    if (j == 0) {
        int lo = 0, hi = N;
        while (lo < hi) { int mid = (lo + hi) >> 1; if (batch[mid] < g) lo = mid + 1; else hi = mid; }
        const int start = lo;
        hi = N;
        while (lo < hi) { int mid = (lo + hi) >> 1; if (batch[mid] < g + 1) lo = mid + 1; else hi = mid; }
        scnt = lo - start;
    }
    __syncthreads();
    const float c = fmaxf((float)scnt, 1.0f);
    sp[j] = pooled[g * 64 + j] / c;
    __syncthreads();
    if (j < 8) {
        float acc = bl[j];
#pragma unroll
        for (int k = 0; k < 64; ++k) acc += sp[k] * Wl[k * 8 + j];
        out[g * 8 + j] = acc;
    }
}

extern "C" void kernel_launch(void* const* d_in, const int* in_sizes, int n_in,
                              void* d_out, int out_size, void* d_ws, size_t ws_size,
                              hipStream_t stream) {
    const float* x      = (const float*)d_in[0];
    const int*   ei     = (const int*)  d_in[1];  // [2,E]: src then dst
    const float* w      = (const float*)d_in[2];
    const int*   batch  = (const int*)  d_in[3];
    const float* W1root = (const float*)d_in[4];
    const float* W1rel  = (const float*)d_in[5];
    const float* b1     = (const float*)d_in[6];
    const float* W2root = (const float*)d_in[7];
    const float* W2rel  = (const float*)d_in[8];
    const float* b2     = (const float*)d_in[9];
    const float* Wl     = (const float*)d_in[10];
    const float* bl     = (const float*)d_in[11];
    float* out = (float*)d_out;

    const int E = in_sizes[2];      // 1,250,000
    const int N = in_sizes[3];      // 100,000
    const int* src = ei;
    const int* dst = ei + E;

    // Workspace layout
    unsigned short* xB   = (unsigned short*)d_ws;          // [N*64] bf16
    unsigned short* x1B  = xB + (size_t)N * 64;            // [N*64]
    int2*  edata    = (int2*)(x1B + (size_t)N * 64);       // [E]
    unsigned short* Bt1 = (unsigned short*)(edata + E);    // [64*128]
    unsigned short* Bt2 = Bt1 + 64 * 128;                  // [64*128]
    int*   rowStart = (int*)(Bt2 + 64 * 128);              // [N+1]
    int*   rowCnt   = rowStart + (N + 1);                  // [N]
    int*   cursor   = rowCnt + N;                          // [N]
    int*   blockSum = cursor + N;                          // [256]
    float* pooled   = (float*)(blockSum + 256);            // [512*64]

    const int histBlocks = (E + 2047) / 2048;              // 611
    const int xElems = N * 16;                              // float4 count
    const int xBlocks = (xElems + 255) / 256;               // 6250
    const int nScan = (N + 511) / 512;                      // 196

    // ---- build + prep (per-node direct: hist -> scan -> scatter) ----
    (void)hipMemsetAsync(rowCnt, 0, (size_t)N * sizeof(int), stream);
    prep1_kernel<<<histBlocks + xBlocks + 8, 256, 0, stream>>>(
        dst, rowCnt, E, histBlocks,
        x, xB, xElems, xBlocks,
        W1rel, W1root, W2rel, W2root, Bt1, Bt2);
    scan1_kernel<<<nScan, 512, 0, stream>>>(rowCnt, rowStart, blockSum, N);
    scan2_kernel<<<1, 256, 0, stream>>>(blockSum, nScan, rowStart, N, E);
    scan3_kernel<<<nScan, 512, 0, stream>>>(rowStart, blockSum, cursor, pooled, N);
    scatter_kernel<<<histBlocks, 256, 0, stream>>>(src, dst, w, cursor, edata, E);

    const int fBlocks = (N + 31) / 32;   // 3125
    // ---- Layer 1: fused gather+transform+store ----
    fused_layer<0><<<fBlocks, 512, 0, stream>>>(xB, rowStart, edata, Bt1, b1,
                                                x1B, nullptr, nullptr, N);
    // ---- Layer 2: fused gather+transform+pool ----
    fused_layer<1><<<fBlocks, 512, 0, stream>>>(x1B, rowStart, edata, Bt2, b2,
                                                nullptr, batch, pooled, N);
    // ---- Pool + classify ----
    final_kernel<<<NUM_GRAPHS, 64, 0, stream>>>(pooled, batch, N, Wl, bl, out);
}

// Round 8
// 257.796 us; speedup vs baseline: 1.4961x; 1.4961x over previous
//
#include <hip/hip_runtime.h>

#define LEAKY_SLOPE 0.01f
#define NUM_GRAPHS 512
#define TILE 4096            // edges per partition block
#define NB_MAX 512           // max dst buckets (N <= 131072)
#define SEG 4096             // tmp segment capacity per bucket (mean 3200, ~14 sigma headroom)
#define POOL_SPAN 8          // graphs per block staged in LDS (overflow -> global)

typedef __attribute__((ext_vector_type(8))) short short8;   // 8 x bf16 (4 VGPRs)
typedef __attribute__((ext_vector_type(4))) float f32x4;    // MFMA C/D

static __device__ __forceinline__ unsigned short f2bf(float f) {
    unsigned u = __float_as_uint(f);
    u += 0x7FFFu + ((u >> 16) & 1u);
    return (unsigned short)(u >> 16);
}
static __device__ __forceinline__ float bf2f(unsigned short h) {
    return __uint_as_float(((unsigned)h) << 16);
}

static __device__ __forceinline__ int wave_incl_scan(int v, int lane) {
#pragma unroll
    for (int off = 1; off < 64; off <<= 1) {
        int t = __shfl_up(v, off, 64);
        if (lane >= off) v += t;
    }
    return v;
}

// ---------------------------------------------------------------------------
// curinit: cursor[b] = b*SEG (segmented tmp bases) + zero pooled. No deps.
// ---------------------------------------------------------------------------
__global__ __launch_bounds__(512)
void curinit_kernel(int* __restrict__ cursor, float* __restrict__ pooled, int NB) {
    const int t = threadIdx.x;
    if (t < NB) cursor[t] = t * SEG;
    float4 z = make_float4(0.f, 0.f, 0.f, 0.f);
#pragma unroll
    for (int i = 0; i < 16; ++i)
        ((float4*)pooled)[t * 16 + i] = z;
}

// ---------------------------------------------------------------------------
// p1x: range-split kernel = p1b radix partition into SEGMENTED tmp (blocks
// 0..histBlocks-1, dispatched first) || x->bf16 convert || W->Bt pack.
// p1b payload: .x = src | (dst&255)<<20, .y = w bits. No global hist needed:
// cursor[b] pre-set to b*SEG.
// ---------------------------------------------------------------------------
__global__ __launch_bounds__(256)
void p1x_kernel(const int* __restrict__ src, const int* __restrict__ dst,
                const float* __restrict__ w, int* __restrict__ cursor,
                int2* __restrict__ tmp, int E, int NB, int histBlocks,
                const float* __restrict__ x, unsigned short* __restrict__ xB,
                int xElems, int xBlocks,
                const float* __restrict__ W1rel, const float* __restrict__ W1root,
                const float* __restrict__ W2rel, const float* __restrict__ W2root,
                unsigned short* __restrict__ Bt1, unsigned short* __restrict__ Bt2) {
    const int bid = blockIdx.x;
    if (bid < histBlocks) {
        __shared__ int h[NB_MAX];
        __shared__ int cur[NB_MAX];
        __shared__ int lstart[NB_MAX];
        __shared__ int gbase[NB_MAX];
        __shared__ int ws[4];
        __shared__ int2 pay[TILE];
        __shared__ unsigned short bk[TILE];

        for (int t = threadIdx.x; t < NB_MAX; t += 256) h[t] = 0;
        __syncthreads();

        const int base = bid * TILE;
        int   myb[TILE / 256];
        int   myp[TILE / 256];
        float myw[TILE / 256];
#pragma unroll
        for (int i = 0; i < TILE / 256; ++i) {
            int e = base + i * 256 + threadIdx.x;
            if (e < E) {
                int d = dst[e];
                myb[i] = d >> 8;
                myp[i] = src[e] | ((d & 255) << 20);
                myw[i] = w[e];
                atomicAdd(&h[myb[i]], 1);
            } else {
                myb[i] = -1;
            }
        }
        __syncthreads();

        {   // exclusive scan of h[0..511] (thread t owns 2t, 2t+1)
            const int t = threadIdx.x, lane = t & 63, wid = t >> 6;
            int a = h[2 * t], b = h[2 * t + 1];
            int s = wave_incl_scan(a + b, lane);
            if (lane == 63) ws[wid] = s;
            __syncthreads();
            int add = 0;
            for (int i = 0; i < wid; ++i) add += ws[i];
            int excl = s + add - (a + b);
            lstart[2 * t] = excl;
            lstart[2 * t + 1] = excl + a;
            cur[2 * t] = excl;
            cur[2 * t + 1] = excl + a;
        }
        __syncthreads();

#pragma unroll
        for (int i = 0; i < TILE / 256; ++i) {
            if (myb[i] >= 0) {
                int p = atomicAdd(&cur[myb[i]], 1);
                pay[p] = make_int2(myp[i], __float_as_int(myw[i]));
                bk[p] = (unsigned short)myb[i];
            }
        }
        __syncthreads();

        for (int t = threadIdx.x; t < NB; t += 256) {
            int c = h[t];
            if (c) gbase[t] = atomicAdd(&cursor[t], c);
        }
        __syncthreads();

        const int total = min(TILE, E - base);
        for (int s2 = threadIdx.x; s2 < total; s2 += 256) {
            int b2 = bk[s2];
            tmp[gbase[b2] + s2 - lstart[b2]] = pay[s2];
        }
    } else if (bid < histBlocks + xBlocks) {
        int i = (bid - histBlocks) * 256 + threadIdx.x;
        if (i < xElems) {
            float4 f = ((const float4*)x)[i];
            ushort4 o = make_ushort4(f2bf(f.x), f2bf(f.y), f2bf(f.z), f2bf(f.w));
            ((ushort4*)xB)[i] = o;
        }
    } else {
        int b2 = bid - histBlocks - xBlocks;            // 0..7
        for (int idx = b2 * 2048 + threadIdx.x; idx < (b2 + 1) * 2048; idx += 256) {
            int which = idx >> 13;
            int j = idx & 8191;
            int n = j >> 7, k = j & 127;
            const float* Wr = which ? W2rel : W1rel;
            const float* Wo = which ? W2root : W1root;
            float v = (k < 64) ? Wr[k * 64 + n] : Wo[(k - 64) * 64 + n];
            (which ? Bt2 : Bt1)[j] = f2bf(v);
        }
    }
}

// ---------------------------------------------------------------------------
// bscan2: bucket counts from cursor (cursor[b]-b*SEG) -> exclusive scan ->
// bucketBase; rowStart[N]=E.
// ---------------------------------------------------------------------------
__global__ __launch_bounds__(512)
void bscan2_kernel(const int* __restrict__ cursor, int* __restrict__ bucketBase,
                   int* __restrict__ rowStart, int N, int E, int NB) {
    __shared__ int ws[8];
    const int t = threadIdx.x, lane = t & 63, wid = t >> 6;
    int v = (t < NB) ? (cursor[t] - t * SEG) : 0;
    int s = wave_incl_scan(v, lane);
    if (lane == 63) ws[wid] = s;
    __syncthreads();
    int add = 0;
    for (int i = 0; i < wid; ++i) add += ws[i];
    if (t < NB) bucketBase[t] = s + add - v;
    if (t == 0) rowStart[N] = E;
}

// ---------------------------------------------------------------------------
// p2: one block per bucket, 512 threads. Reads tmp segment [b*SEG, b*SEG+cnt),
// LDS hist of 256 local dst -> scan -> rowStart + dense dst-sorted edata at
// bucketBase[b].
// ---------------------------------------------------------------------------
__global__ __launch_bounds__(512)
void p2_build(const int2* __restrict__ tmp, const int* __restrict__ bucketBase,
              int* __restrict__ rowStart, int2* __restrict__ edata,
              int N, int E, int NB) {
    const int b = blockIdx.x;
    const int sOut = bucketBase[b];
    const int cnt  = ((b + 1 < NB) ? bucketBase[b + 1] : E) - sOut;
    const int sIn  = b * SEG;
    __shared__ int h[256];
    __shared__ int cur[256];
    __shared__ int ws[8];
    if (threadIdx.x < 256) h[threadIdx.x] = 0;
    __syncthreads();
    for (int j = threadIdx.x; j < cnt; j += 512) {
        int dl = (tmp[sIn + j].x >> 20) & 255;
        atomicAdd(&h[dl], 1);
    }
    __syncthreads();
    const int t = threadIdx.x, lane = t & 63, wid = t >> 6;
    int v = (t < 256) ? h[t] : 0;
    int sc = wave_incl_scan(v, lane);
    if (lane == 63) ws[wid] = sc;
    __syncthreads();
    int add = 0;
    for (int i = 0; i < wid; ++i) add += ws[i];
    int excl = sc + add - v;
    if (t < 256) {
        const int node = b * 256 + t;
        if (node < N) rowStart[node] = sOut + excl;
        cur[t] = excl;
    }
    __syncthreads();
    for (int j = threadIdx.x; j < cnt; j += 512) {
        int2 v2 = tmp[sIn + j];
        int dl = (v2.x >> 20) & 255;
        int p = atomicAdd(&cur[dl], 1);
        edata[sOut + p] = make_int2(v2.x & 0x1FFFF, v2.y);
    }
}

// ---------------------------------------------------------------------------
// fused_layer<POOL>: gather + transform (R5 shape, unchanged). Block = 32
// nodes, 512 threads = 8 waves; wave w gathers nodes 4w..4w+3 as 2 pairs
// with both nodes' loads in flight; transform is the 8-way (s,t) tile split.
// ---------------------------------------------------------------------------
template <int POOL>
__global__ __launch_bounds__(512)
void fused_layer(const unsigned short* __restrict__ xin,
                 const int* __restrict__ rowStart,
                 const int2* __restrict__ edata,
                 const unsigned short* __restrict__ Bt,
                 const float* __restrict__ bias,
                 unsigned short* __restrict__ xoutB,
                 const int* __restrict__ batch,
                 float* __restrict__ pooled, int N) {
    const int lane = threadIdx.x & 63;
    const int wave = threadIdx.x >> 6;          // 0..7
    const int grp  = lane >> 4;                 // edge slot in gather / quad in MFMA
    const int l16  = lane & 15;                 // feature-chunk lane / row lane
    const int f4   = l16 * 4;
    const int m0   = (int)blockIdx.x * 32;      // block's node base

    __shared__ __align__(16) unsigned short aggL[32][72];
    __shared__ float lpool[POOL_SPAN * 64];

    int gmin = 0;
    if (POOL) {
        gmin = batch[m0 < N ? m0 : N - 1];
        for (int i = threadIdx.x; i < POOL_SPAN * 64; i += 512) lpool[i] = 0.f;
    }

    // ---- gather phase: wave w owns local nodes 4w .. 4w+3, as 2 pairs ----
    int rsv = 0;
    if (lane <= 32) {
        int rn = m0 + lane;
        rsv = rowStart[rn < N ? rn : N];
    }
#pragma unroll
    for (int p = 0; p < 2; ++p) {
        const int ia = (wave << 2) + (p << 1);     // local node a; b = ia+1
        const int sa = __shfl(rsv, ia, 64);
        const int ea = __shfl(rsv, ia + 1, 64);
        const int sb = ea;
        const int eb = __shfl(rsv, ia + 2, 64);

        float aA0 = 0.f, aA1 = 0.f, aA2 = 0.f, aA3 = 0.f;
        float aB0 = 0.f, aB1 = 0.f, aB2 = 0.f, aB3 = 0.f;
        int ja = sa, jb = sb;
        while (ja < ea || jb < eb) {
            const bool da = ja < ea;
            const bool db = jb < eb;
            int2 edA[4], edB[4];
            if (da) {
#pragma unroll
                for (int u = 0; u < 4; ++u) {
                    int ii = ja + u * 4 + grp;
                    edA[u] = edata[ii < ea ? ii : sa];
                }
            }
            if (db) {
#pragma unroll
                for (int u = 0; u < 4; ++u) {
                    int ii = jb + u * 4 + grp;
                    edB[u] = edata[ii < eb ? ii : sb];
                }
            }
            ushort4 rA[4], rB[4];
            if (da) {
#pragma unroll
                for (int u = 0; u < 4; ++u)
                    rA[u] = *(const ushort4*)(xin + (size_t)edA[u].x * 64 + f4);
            }
            if (db) {
#pragma unroll
                for (int u = 0; u < 4; ++u)
                    rB[u] = *(const ushort4*)(xin + (size_t)edB[u].x * 64 + f4);
            }
            if (da) {
#pragma unroll
                for (int u = 0; u < 4; ++u) {
                    float wv = (ja + u * 4 + grp < ea) ? __int_as_float(edA[u].y) : 0.0f;
                    aA0 += bf2f(rA[u].x) * wv;  aA1 += bf2f(rA[u].y) * wv;
                    aA2 += bf2f(rA[u].z) * wv;  aA3 += bf2f(rA[u].w) * wv;
                }
                ja += 16;
            }
            if (db) {
#pragma unroll
                for (int u = 0; u < 4; ++u) {
                    float wv = (jb + u * 4 + grp < eb) ? __int_as_float(edB[u].y) : 0.0f;
                    aB0 += bf2f(rB[u].x) * wv;  aB1 += bf2f(rB[u].y) * wv;
                    aB2 += bf2f(rB[u].z) * wv;  aB3 += bf2f(rB[u].w) * wv;
                }
                jb += 16;
            }
        }
        aA0 += __shfl_xor(aA0, 16, 64);  aA1 += __shfl_xor(aA1, 16, 64);
        aA2 += __shfl_xor(aA2, 16, 64);  aA3 += __shfl_xor(aA3, 16, 64);
        aA0 += __shfl_xor(aA0, 32, 64);  aA1 += __shfl_xor(aA1, 32, 64);
        aA2 += __shfl_xor(aA2, 32, 64);  aA3 += __shfl_xor(aA3, 32, 64);
        aB0 += __shfl_xor(aB0, 16, 64);  aB1 += __shfl_xor(aB1, 16, 64);
        aB2 += __shfl_xor(aB2, 16, 64);  aB3 += __shfl_xor(aB3, 16, 64);
        aB0 += __shfl_xor(aB0, 32, 64);  aB1 += __shfl_xor(aB1, 32, 64);
        aB2 += __shfl_xor(aB2, 32, 64);  aB3 += __shfl_xor(aB3, 32, 64);
        if (grp == 0) {
            *(ushort4*)(&aggL[ia][f4]) =
                make_ushort4(f2bf(aA0), f2bf(aA1), f2bf(aA2), f2bf(aA3));
            *(ushort4*)(&aggL[ia + 1][f4]) =
                make_ushort4(f2bf(aB0), f2bf(aB1), f2bf(aB2), f2bf(aB3));
        }
    }

    __syncthreads();   // aggL complete (and lpool zero-init for POOL)

    // ---- transform phase: wave w -> tile (s = w>>2 row half, t = w&3) ----
    {
        const int s = wave >> 2;
        const int t = wave & 3;
        short8 bf[4];
#pragma unroll
        for (int k = 0; k < 4; ++k)
            bf[k] = *(const short8*)(Bt + (t * 16 + l16) * 128 + k * 32 + grp * 8);

        f32x4 acc = (f32x4){0.f, 0.f, 0.f, 0.f};
        int row = m0 + s * 16 + l16;
        int rowc = row < N ? row : N - 1;
        const unsigned short* xrow = xin + (size_t)rowc * 64;
        short8 af[4];
        af[0] = *(const short8*)(&aggL[s * 16 + l16][grp * 8]);
        af[1] = *(const short8*)(&aggL[s * 16 + l16][32 + grp * 8]);
        af[2] = *(const short8*)(xrow + grp * 8);
        af[3] = *(const short8*)(xrow + 32 + grp * 8);
#pragma unroll
        for (int k = 0; k < 4; ++k) {
            if (POOL == 0)
                acc = __builtin_amdgcn_mfma_f32_16x16x32_bf16(bf[k], af[k], acc, 0, 0, 0);
            else
                acc = __builtin_amdgcn_mfma_f32_16x16x32_bf16(af[k], bf[k], acc, 0, 0, 0);
        }

        if (POOL == 0) {
            const int node = m0 + s * 16 + l16;
            if (node < N) {
                const float4 bb = *(const float4*)(bias + t * 16 + grp * 4);
                float v0 = acc[0] + bb.x;
                float v1 = acc[1] + bb.y;
                float v2 = acc[2] + bb.z;
                float v3 = acc[3] + bb.w;
                v0 = (v0 > 0.f) ? v0 : LEAKY_SLOPE * v0;
                v1 = (v1 > 0.f) ? v1 : LEAKY_SLOPE * v1;
                v2 = (v2 > 0.f) ? v2 : LEAKY_SLOPE * v2;
                v3 = (v3 > 0.f) ? v3 : LEAKY_SLOPE * v3;
                ushort4 o = make_ushort4(f2bf(v0), f2bf(v1), f2bf(v2), f2bf(v3));
                *(ushort4*)(xoutB + (size_t)node * 64 + t * 16 + grp * 4) = o;
            }
        } else {
            const int col = t * 16 + l16;
            const float b = bias[col];
            const int rowbase = m0 + s * 16 + grp * 4;
            float v[4]; int g[4]; int nv = 0;
#pragma unroll
            for (int r = 0; r < 4; ++r) {
                int row2 = rowbase + r;
                if (row2 < N) {
                    float a = acc[r] + b;
                    a = (a > 0.0f) ? a : LEAKY_SLOPE * a;
                    v[nv] = a;
                    g[nv] = batch[row2];
                    ++nv;
                }
            }
            if (nv == 4 && g[0] == g[3]) {
                int gl = g[0] - gmin;
                float sum = v[0] + v[1] + v[2] + v[3];
                if (gl < POOL_SPAN) atomicAdd(&lpool[gl * 64 + col], sum);
                else                atomicAdd(&pooled[g[0] * 64 + col], sum);
            } else {
                for (int r = 0; r < nv; ++r) {
                    int gl = g[r] - gmin;
                    if (gl < POOL_SPAN) atomicAdd(&lpool[gl * 64 + col], v[r]);
                    else                atomicAdd(&pooled[g[r] * 64 + col], v[r]);
                }
            }
        }
    }

    if (POOL) {
        __syncthreads();
        for (int i = threadIdx.x; i < POOL_SPAN * 64; i += 512) {
            float vv = lpool[i];
            if (vv != 0.0f)
                atomicAdd(&pooled[(gmin + (i >> 6)) * 64 + (i & 63)], vv);
        }
    }
}

// ---------------------------------------------------------------------------
// Final: cnt via binary search on sorted batch; tiny GEMM epilogue.
// ---------------------------------------------------------------------------
__global__ __launch_bounds__(64)
void final_kernel(const float* __restrict__ pooled, const int* __restrict__ batch,
                  int N, const float* __restrict__ Wl, const float* __restrict__ bl,
                  float* __restrict__ out) {
    const int g = blockIdx.x;
    const int j = threadIdx.x;
    __shared__ float sp[64];
    __shared__ int scnt;
    if (j == 0) {
        int lo = 0, hi = N;
        while (lo < hi) { int mid = (lo + hi) >> 1; if (batch[mid] < g) lo = mid + 1; else hi = mid; }
        const int start = lo;
        hi = N;
        while (lo < hi) { int mid = (lo + hi) >> 1; if (batch[mid] < g + 1) lo = mid + 1; else hi = mid; }
        scnt = lo - start;
    }
    __syncthreads();
    const float c = fmaxf((float)scnt, 1.0f);
    sp[j] = pooled[g * 64 + j] / c;
    __syncthreads();
    if (j < 8) {
        float acc = bl[j];
#pragma unroll
        for (int k = 0; k < 64; ++k) acc += sp[k] * Wl[k * 8 + j];
        out[g * 8 + j] = acc;
    }
}

extern "C" void kernel_launch(void* const* d_in, const int* in_sizes, int n_in,
                              void* d_out, int out_size, void* d_ws, size_t ws_size,
                              hipStream_t stream) {
    const float* x      = (const float*)d_in[0];
    const int*   ei     = (const int*)  d_in[1];  // [2,E]: src then dst
    const float* w      = (const float*)d_in[2];
    const int*   batch  = (const int*)  d_in[3];
    const float* W1root = (const float*)d_in[4];
    const float* W1rel  = (const float*)d_in[5];
    const float* b1     = (const float*)d_in[6];
    const float* W2root = (const float*)d_in[7];
    const float* W2rel  = (const float*)d_in[8];
    const float* b2     = (const float*)d_in[9];
    const float* Wl     = (const float*)d_in[10];
    const float* bl     = (const float*)d_in[11];
    float* out = (float*)d_out;

    const int E = in_sizes[2];      // 1,250,000
    const int N = in_sizes[3];      // 100,000
    const int* src = ei;
    const int* dst = ei + E;
    const int NB = (N + 255) / 256; // 391 dst buckets

    // Workspace layout
    unsigned short* xB   = (unsigned short*)d_ws;          // [N*64] bf16
    unsigned short* x1B  = xB + (size_t)N * 64;            // [N*64]
    int2*  tmp      = (int2*)(x1B + (size_t)N * 64);       // [NB*SEG] segmented
    int2*  edata    = tmp + (size_t)NB_MAX * SEG;          // [E]
    unsigned short* Bt1 = (unsigned short*)(edata + E);    // [64*128]
    unsigned short* Bt2 = Bt1 + 64 * 128;                  // [64*128]
    int*   rowStart = (int*)(Bt2 + 64 * 128);              // [N+1]
    int*   bucketBase = rowStart + (N + 1);                // [512]
    int*   cursor     = bucketBase + NB_MAX;               // [512]
    float* pooled   = (float*)(cursor + NB_MAX);           // [512*64]

    const int histBlocks = (E + TILE - 1) / TILE;          // 306
    const int xElems = N * 16;                              // float4 count
    const int xBlocks = (xElems + 255) / 256;               // 6250

    // ---- build + prep (hist-free: curinit -> p1x(seg tmp) -> bscan2 -> p2) ----
    curinit_kernel<<<1, 512, 0, stream>>>(cursor, pooled, NB);
    p1x_kernel<<<histBlocks + xBlocks + 8, 256, 0, stream>>>(
        src, dst, w, cursor, tmp, E, NB, histBlocks,
        x, xB, xElems, xBlocks,
        W1rel, W1root, W2rel, W2root, Bt1, Bt2);
    bscan2_kernel<<<1, 512, 0, stream>>>(cursor, bucketBase, rowStart, N, E, NB);
    p2_build<<<NB, 512, 0, stream>>>(tmp, bucketBase, rowStart, edata, N, E, NB);

    const int fBlocks = (N + 31) / 32;   // 3125
    // ---- Layer 1: fused gather+transform+store ----
    fused_layer<0><<<fBlocks, 512, 0, stream>>>(xB, rowStart, edata, Bt1, b1,
                                                x1B, nullptr, nullptr, N);
    // ---- Layer 2: fused gather+transform+pool ----
    fused_layer<1><<<fBlocks, 512, 0, stream>>>(x1B, rowStart, edata, Bt2, b2,
                                                nullptr, batch, pooled, N);
    // ---- Pool + classify ----
    final_kernel<<<NUM_GRAPHS, 64, 0, stream>>>(pooled, batch, N, Wl, bl, out);
}